// Round 5
// baseline (243.443 us; speedup 1.0000x reference)
//
#include <hip/hip_runtime.h>
#include <hip/hip_bf16.h>
#include <math.h>

#define BB 2
#define NN 8192
#define DD 512
#define HH 8
#define DK 64
#define KNB 32
#define BN (BB*NN)          // 16384 rows
#define BHN (BB*HH*NN)      // 131072 (b,h,n) tuples

typedef __attribute__((ext_vector_type(8))) _Float16 f16x8;   // 8 f16 in 4 VGPRs
typedef __attribute__((ext_vector_type(2))) _Float16 f16x2;
typedef __attribute__((ext_vector_type(4))) float f32x4;

#if __has_builtin(__builtin_amdgcn_fdot2)
#define HAS_FDOT2 1
#endif

__device__ __forceinline__ unsigned short f2h(float f) {
    return __builtin_bit_cast(unsigned short, (_Float16)f);
}
__device__ __forceinline__ f16x2 u2h2(unsigned u) {
    return __builtin_bit_cast(f16x2, u);
}
__device__ __forceinline__ float h2f_lo(unsigned u) {
    return (float)__builtin_bit_cast(_Float16, (unsigned short)(u & 0xffffu));
}
__device__ __forceinline__ float h2f_hi(unsigned u) {
    return (float)__builtin_bit_cast(_Float16, (unsigned short)(u >> 16));
}
// dot of packed f16 pairs with fp32 accumulate
__device__ __forceinline__ float dot2h(unsigned a, unsigned b, float c) {
#ifdef HAS_FDOT2
    return __builtin_amdgcn_fdot2(u2h2(a), u2h2(b), c, false);
#else
    c = fmaf(h2f_lo(a), h2f_lo(b), c);
    return fmaf(h2f_hi(a), h2f_hi(b), c);
#endif
}

// async global->LDS, 16B per lane. LDS dest must be wave-uniform base; HW adds lane*16.
__device__ __forceinline__ void gload_lds16(const void* gptr, void* lptr) {
    __builtin_amdgcn_global_load_lds(
        (const __attribute__((address_space(1))) unsigned int*)gptr,
        (__attribute__((address_space(3))) unsigned int*)lptr,
        16, 0, 0);
}

// ---------------- fp32 -> f16 converter (x + all weights, one launch) ----------------
__global__ __launch_bounds__(256) void cvt_all(
    const float* __restrict__ x,
    const float* __restrict__ Wq, const float* __restrict__ Wk,
    const float* __restrict__ Wv, const float* __restrict__ Wo,
    unsigned short* __restrict__ Xb, unsigned short* __restrict__ Wfb,
    unsigned short* __restrict__ Wob)
{
    const int blk = blockIdx.x;
    const float* src;
    unsigned short* dst;
    int off;
    if (blk < 8192) {
        off = (blk * 256 + threadIdx.x) * 4;
        src = x; dst = Xb;
    } else {
        const int e = ((blk - 8192) * 256 + threadIdx.x) * 4;   // over 4*262144
        const int t = e >> 18;
        off = e & 262143;
        src = (t == 0) ? Wq : (t == 1) ? Wk : (t == 2) ? Wv : Wo;
        dst = (t < 3) ? (Wfb + (size_t)t * 262144) : Wob;
    }
    const float4 v = *(const float4*)(src + off);
    ushort4 u;
    u.x = f2h(v.x); u.y = f2h(v.y); u.z = f2h(v.z); u.w = f2h(v.w);
    *(ushort4*)(dst + off) = u;
}

// ---------------- Kernel 1: fused QKV projection + LayerNorm, f16 MFMA ----------------
__global__ __launch_bounds__(256) void gemm_qkv(
    const unsigned short* __restrict__ Xb, const unsigned short* __restrict__ Wfb,
    unsigned short* __restrict__ Qh, unsigned short* __restrict__ Kh,
    unsigned short* __restrict__ Vh)
{
    __shared__ unsigned short Als[128 * 32];   // 8 KB
    __shared__ unsigned short Bls[128 * 32];   // 8 KB
    const int tid  = threadIdx.x;
    const int wave = tid >> 6, lane = tid & 63;
    const int wm = wave >> 1, wn = wave & 1;
    const int quad = lane >> 4, r = lane & 15;
    const int row0 = blockIdx.x * 128;
    const int c0   = blockIdx.y * 128;        // 128 | 512 so tile is within one tensor

    f32x4 acc[4][4];
    #pragma unroll
    for (int i = 0; i < 4; ++i)
        #pragma unroll
        for (int j = 0; j < 4; ++j) acc[i][j] = (f32x4)0.f;

    const char* Ab = (const char*)Xb;
    const char* Bb = (const char*)Wfb;

    for (int k0 = 0; k0 < 512; k0 += 32) {
        __syncthreads();
        #pragma unroll
        for (int q = 0; q < 2; ++q) {
            const int li = q * 4096 + wave * 1024 + lane * 16;
            const int rr = li >> 6, off = li & 63;
            gload_lds16(Ab + (size_t)(row0 + rr) * 1024 + k0 * 2 + off,
                        (char*)Als + (q * 4096 + wave * 1024));
            gload_lds16(Bb + (size_t)(c0 + rr) * 1024 + k0 * 2 + off,
                        (char*)Bls + (q * 4096 + wave * 1024));
        }
        __syncthreads();

        f16x8 af[4], bf[4];
        #pragma unroll
        for (int i = 0; i < 4; ++i)
            af[i] = *(const f16x8*)(&Als[(wm * 64 + i * 16 + r) * 32 + quad * 8]);
        #pragma unroll
        for (int j = 0; j < 4; ++j)
            bf[j] = *(const f16x8*)(&Bls[(wn * 64 + j * 16 + r) * 32 + quad * 8]);
        #pragma unroll
        for (int i = 0; i < 4; ++i)
            #pragma unroll
            for (int j = 0; j < 4; ++j)
                acc[i][j] = __builtin_amdgcn_mfma_f32_16x16x32_f16(af[i], bf[j], acc[i][j], 0, 0, 0);
    }

    const int tensor = c0 >> 9;   // block-uniform: 0=Q 1=K 2=V
    unsigned short* OutH = (tensor == 0) ? Qh : (tensor == 1) ? Kh : Vh;

    float mu[4][4], rs[4][4];
    if (tensor < 2) {
        #pragma unroll
        for (int i = 0; i < 4; ++i) {
            #pragma unroll
            for (int reg = 0; reg < 4; ++reg) {
                float sm = acc[i][0][reg] + acc[i][1][reg] + acc[i][2][reg] + acc[i][3][reg];
                sm += __shfl_xor(sm, 1); sm += __shfl_xor(sm, 2);
                sm += __shfl_xor(sm, 4); sm += __shfl_xor(sm, 8);
                const float muv = sm * (1.f / 64.f);
                float qv = 0.f;
                #pragma unroll
                for (int j = 0; j < 4; ++j) {
                    const float dv = acc[i][j][reg] - muv;
                    qv = fmaf(dv, dv, qv);
                }
                qv += __shfl_xor(qv, 1); qv += __shfl_xor(qv, 2);
                qv += __shfl_xor(qv, 4); qv += __shfl_xor(qv, 8);
                mu[i][reg] = muv;
                rs[i][reg] = rsqrtf(qv * (1.f / 64.f) + 1e-5f);
            }
        }
    }

    // C/D layout col=lane&15, row=quad*4+reg (verified m89).
    #pragma unroll
    for (int i = 0; i < 4; ++i) {
        #pragma unroll
        for (int j = 0; j < 4; ++j) {
            const int cc = (c0 & 511) + wn * 64 + j * 16 + r;
            const int h = cc >> 6, d = cc & 63;
            #pragma unroll
            for (int reg = 0; reg < 4; ++reg) {
                const int row = row0 + wm * 64 + i * 16 + quad * 4 + reg;
                const int b = row >> 13, n = row & 8191;
                float v = acc[i][j][reg];
                if (tensor < 2) v = (v - mu[i][reg]) * rs[i][reg];
                OutH[(((size_t)(b * HH + h) * NN + n) << 6) + d] = f2h(v);
            }
        }
    }
}

// ---------------- Kernel 2: gather-attention, 2 tuples per wave ----------------
// Each wave handles (bh, n0) and (bh, n0+1): two fully-independent dependency
// chains interleave (2x loads in flight) to cover L1/L2 latency at half the
// wave count. Score: 64 lanes = 32 neighbors x 2 half-rows, fdot2. V phase:
// packed (g,p) pairs, 1 readlane each per 2 neighbors.
// XCD swizzle: physical block p -> logical (p&7)*2048 + (p>>3).
__global__ __launch_bounds__(256) void attn(
    const unsigned short* __restrict__ Qh, const unsigned short* __restrict__ Kh,
    const unsigned short* __restrict__ Vh,
    const int* __restrict__ idx, unsigned short* __restrict__ Ob)
{
    const int p = blockIdx.x;                       // 0..16383
    const int L = ((p & 7) << 11) | (p >> 3);       // XCD-contiguous logical id
    const int wv = L * 4 + (threadIdx.x >> 6);      // 0..65535
    const int lane = threadIdx.x & 63;
    const int bh = wv >> 12;                        // 2 tuples/wave, 8192 n per bh
    const int n0 = (wv & 4095) * 2;
    const size_t base = (size_t)bh * NN * DK;

    const int k    = lane >> 1;
    const int half = lane & 1;

    int g[2];
    #pragma unroll
    for (int t = 0; t < 2; ++t) g[t] = idx[(n0 + t) * KNB + k];   // pair-duplicated

    // Score phase: two independent half-row dots (32 elems = 16 packed pairs each)
    float s[2];
    #pragma unroll
    for (int t = 0; t < 2; ++t) {
        const uint4* q4 = (const uint4*)(Qh + base + ((size_t)(n0 + t) << 6) + half * 32);
        const uint4* k4 = (const uint4*)(Kh + base + ((size_t)g[t] << 6) + half * 32);
        float acc = 0.f;
        #pragma unroll
        for (int c = 0; c < 4; ++c) {
            const uint4 qa = q4[c], ka = k4[c];
            acc = dot2h(qa.x, ka.x, acc);
            acc = dot2h(qa.y, ka.y, acc);
            acc = dot2h(qa.z, ka.z, acc);
            acc = dot2h(qa.w, ka.w, acc);
        }
        s[t] = (acc + __shfl_xor(acc, 1)) * 0.125f;   // 1/sqrt(64)
    }

    // Softmax over 32 distinct neighbors (values pair-duplicated), both tuples
    // interleaved so the shuffle latencies overlap.
    float m[2] = {s[0], s[1]};
    #pragma unroll
    for (int off = 2; off <= 32; off <<= 1) {
        #pragma unroll
        for (int t = 0; t < 2; ++t) m[t] = fmaxf(m[t], __shfl_xor(m[t], off));
    }
    float e[2], tot[2];
    #pragma unroll
    for (int t = 0; t < 2; ++t) { e[t] = __expf(s[t] - m[t]); tot[t] = e[t]; }
    #pragma unroll
    for (int off = 2; off <= 32; off <<= 1) {
        #pragma unroll
        for (int t = 0; t < 2; ++t) tot[t] += __shfl_xor(tot[t], off);
    }

    // Pack neighbor-pair (p, g): lane 4j holds p_{2j}|p_{2j+1}<<16, g likewise.
    unsigned pp[2], gg[2];
    #pragma unroll
    for (int t = 0; t < 2; ++t) {
        const unsigned prh = (unsigned)f2h(e[t] / tot[t]);
        pp[t] = prh | (((unsigned)__shfl_xor((int)prh, 2)) << 16);
        gg[t] = (unsigned)g[t] | (((unsigned)__shfl_xor(g[t], 2)) << 16);
    }

    // V accumulation: lane d accumulates sum_k p_k * V[g_k][d]; two chains.
    float o[2] = {0.f, 0.f};
    #pragma unroll
    for (int j = 0; j < 16; ++j) {
        #pragma unroll
        for (int t = 0; t < 2; ++t) {
            const unsigned gpair = (unsigned)__builtin_amdgcn_readlane((int)gg[t], j * 4);
            const unsigned ppair = (unsigned)__builtin_amdgcn_readlane((int)pp[t], j * 4);
            const int g0 = (int)(gpair & 0xffffu), g1 = (int)(gpair >> 16);
            const unsigned v0 = Vh[base + ((size_t)g0 << 6) + lane];
            const unsigned v1 = Vh[base + ((size_t)g1 << 6) + lane];
            o[t] = dot2h(v0 | (v1 << 16), ppair, o[t]);
        }
    }
    const int b = bh >> 3, h = bh & 7;
    #pragma unroll
    for (int t = 0; t < 2; ++t)
        Ob[((size_t)(b * NN + n0 + t)) * DD + h * DK + lane] = f2h(o[t]);
}

// ---------------- Kernel 3: output projection, f16 MFMA ----------------
__global__ __launch_bounds__(256) void gemm_out(
    const unsigned short* __restrict__ Ob, const unsigned short* __restrict__ Wob,
    const float* __restrict__ bout, float* __restrict__ out)
{
    __shared__ unsigned short Als[128 * 32];
    __shared__ unsigned short Bls[128 * 32];
    const int tid  = threadIdx.x;
    const int wave = tid >> 6, lane = tid & 63;
    const int wm = wave >> 1, wn = wave & 1;
    const int quad = lane >> 4, r = lane & 15;
    const int row0 = blockIdx.x * 128;
    const int c0   = blockIdx.y * 128;

    f32x4 acc[4][4];
    #pragma unroll
    for (int i = 0; i < 4; ++i)
        #pragma unroll
        for (int j = 0; j < 4; ++j) acc[i][j] = (f32x4)0.f;

    const char* Ab = (const char*)Ob;
    const char* Bb = (const char*)Wob;

    for (int k0 = 0; k0 < 512; k0 += 32) {
        __syncthreads();
        #pragma unroll
        for (int q = 0; q < 2; ++q) {
            const int li = q * 4096 + wave * 1024 + lane * 16;
            const int rr = li >> 6, off = li & 63;
            gload_lds16(Ab + (size_t)(row0 + rr) * 1024 + k0 * 2 + off,
                        (char*)Als + (q * 4096 + wave * 1024));
            gload_lds16(Bb + (size_t)(c0 + rr) * 1024 + k0 * 2 + off,
                        (char*)Bls + (q * 4096 + wave * 1024));
        }
        __syncthreads();

        f16x8 af[4], bf[4];
        #pragma unroll
        for (int i = 0; i < 4; ++i)
            af[i] = *(const f16x8*)(&Als[(wm * 64 + i * 16 + r) * 32 + quad * 8]);
        #pragma unroll
        for (int j = 0; j < 4; ++j)
            bf[j] = *(const f16x8*)(&Bls[(wn * 64 + j * 16 + r) * 32 + quad * 8]);
        #pragma unroll
        for (int i = 0; i < 4; ++i)
            #pragma unroll
            for (int j = 0; j < 4; ++j)
                acc[i][j] = __builtin_amdgcn_mfma_f32_16x16x32_f16(af[i], bf[j], acc[i][j], 0, 0, 0);
    }

    #pragma unroll
    for (int i = 0; i < 4; ++i) {
        #pragma unroll
        for (int j = 0; j < 4; ++j) {
            const int colg = c0 + wn * 64 + j * 16 + r;
            const float bb = bout[colg];
            #pragma unroll
            for (int reg = 0; reg < 4; ++reg) {
                const int row = row0 + wm * 64 + i * 16 + quad * 4 + reg;
                out[((size_t)row << 9) + colg] = acc[i][j][reg] + bb;
            }
        }
    }
}

extern "C" void kernel_launch(void* const* d_in, const int* in_sizes, int n_in,
                              void* d_out, int out_size, void* d_ws, size_t ws_size,
                              hipStream_t stream)
{
    const float* x    = (const float*)d_in[0];
    const int*   idx  = (const int*)  d_in[1];
    const float* Wq   = (const float*)d_in[2];
    const float* Wk   = (const float*)d_in[3];
    const float* Wv   = (const float*)d_in[4];
    const float* Wout = (const float*)d_in[5];
    const float* bout = (const float*)d_in[6];

    char* ws = (char*)d_ws;
    unsigned short* Qh  = (unsigned short*)(ws);              // 16777216 B
    unsigned short* Kh  = (unsigned short*)(ws + 16777216);   // 16777216 B
    unsigned short* Vh  = (unsigned short*)(ws + 33554432);   // 16777216 B
    unsigned short* Xb  = (unsigned short*)(ws + 50331648);   // 16777216 B; aliased as Ob
    unsigned short* Ob  = Xb;
    unsigned short* Wfb = (unsigned short*)(ws + 67108864);   // 1572864 B (Wq|Wk|Wv rows)
    unsigned short* Wob = (unsigned short*)(ws + 68681728);   // 524288 B
    float* out = (float*)d_out;

    cvt_all<<<9216, 256, 0, stream>>>(x, Wq, Wk, Wv, Wout, Xb, Wfb, Wob);

    dim3 g1(BN / 128, 1536 / 128);
    gemm_qkv<<<g1, 256, 0, stream>>>(Xb, Wfb, Qh, Kh, Vh);

    attn<<<BHN / 8, 256, 0, stream>>>(Qh, Kh, Vh, idx, Ob);

    dim3 g2(BN / 128, 512 / 128);
    gemm_out<<<g2, 256, 0, stream>>>(Ob, Wob, bout, out);
}

// Round 6
// 229.108 us; speedup vs baseline: 1.0626x; 1.0626x over previous
//
#include <hip/hip_runtime.h>
#include <hip/hip_bf16.h>
#include <math.h>

#define BB 2
#define NN 8192
#define DD 512
#define HH 8
#define DK 64
#define KNB 32
#define BN (BB*NN)          // 16384 rows
#define BHN (BB*HH*NN)      // 131072 (b,h,n) tuples

typedef __attribute__((ext_vector_type(8))) _Float16 f16x8;   // 8 f16 in 4 VGPRs
typedef __attribute__((ext_vector_type(2))) _Float16 f16x2;
typedef __attribute__((ext_vector_type(4))) float f32x4;

#if __has_builtin(__builtin_amdgcn_fdot2)
#define HAS_FDOT2 1
#endif

__device__ __forceinline__ unsigned short f2h(float f) {
    return __builtin_bit_cast(unsigned short, (_Float16)f);
}
__device__ __forceinline__ f16x2 u2h2(unsigned u) {
    return __builtin_bit_cast(f16x2, u);
}
__device__ __forceinline__ float h2f_lo(unsigned u) {
    return (float)__builtin_bit_cast(_Float16, (unsigned short)(u & 0xffffu));
}
__device__ __forceinline__ float h2f_hi(unsigned u) {
    return (float)__builtin_bit_cast(_Float16, (unsigned short)(u >> 16));
}
// dot of packed f16 pairs with fp32 accumulate
__device__ __forceinline__ float dot2h(unsigned a, unsigned b, float c) {
#ifdef HAS_FDOT2
    return __builtin_amdgcn_fdot2(u2h2(a), u2h2(b), c, false);
#else
    c = fmaf(h2f_lo(a), h2f_lo(b), c);
    return fmaf(h2f_hi(a), h2f_hi(b), c);
#endif
}

// async global->LDS, 16B per lane. LDS dest must be wave-uniform base; HW adds lane*16.
__device__ __forceinline__ void gload_lds16(const void* gptr, void* lptr) {
    __builtin_amdgcn_global_load_lds(
        (const __attribute__((address_space(1))) unsigned int*)gptr,
        (__attribute__((address_space(3))) unsigned int*)lptr,
        16, 0, 0);
}

// ---------------- fp32 -> f16 converter (x + all weights, one launch) ----------------
__global__ __launch_bounds__(256) void cvt_all(
    const float* __restrict__ x,
    const float* __restrict__ Wq, const float* __restrict__ Wk,
    const float* __restrict__ Wv, const float* __restrict__ Wo,
    unsigned short* __restrict__ Xb, unsigned short* __restrict__ Wfb,
    unsigned short* __restrict__ Wob)
{
    const int blk = blockIdx.x;
    const float* src;
    unsigned short* dst;
    int off;
    if (blk < 8192) {
        off = (blk * 256 + threadIdx.x) * 4;
        src = x; dst = Xb;
    } else {
        const int e = ((blk - 8192) * 256 + threadIdx.x) * 4;   // over 4*262144
        const int t = e >> 18;
        off = e & 262143;
        src = (t == 0) ? Wq : (t == 1) ? Wk : (t == 2) ? Wv : Wo;
        dst = (t < 3) ? (Wfb + (size_t)t * 262144) : Wob;
    }
    const float4 v = *(const float4*)(src + off);
    ushort4 u;
    u.x = f2h(v.x); u.y = f2h(v.y); u.z = f2h(v.z); u.w = f2h(v.w);
    *(ushort4*)(dst + off) = u;
}

// ---------------- Kernel 1: fused QKV projection + LayerNorm, f16 MFMA ----------------
__global__ __launch_bounds__(256) void gemm_qkv(
    const unsigned short* __restrict__ Xb, const unsigned short* __restrict__ Wfb,
    unsigned short* __restrict__ Qh, unsigned short* __restrict__ Kh,
    unsigned short* __restrict__ Vh)
{
    __shared__ unsigned short Als[128 * 32];   // 8 KB
    __shared__ unsigned short Bls[128 * 32];   // 8 KB
    const int tid  = threadIdx.x;
    const int wave = tid >> 6, lane = tid & 63;
    const int wm = wave >> 1, wn = wave & 1;
    const int quad = lane >> 4, r = lane & 15;
    const int row0 = blockIdx.x * 128;
    const int c0   = blockIdx.y * 128;        // 128 | 512 so tile is within one tensor

    f32x4 acc[4][4];
    #pragma unroll
    for (int i = 0; i < 4; ++i)
        #pragma unroll
        for (int j = 0; j < 4; ++j) acc[i][j] = (f32x4)0.f;

    const char* Ab = (const char*)Xb;
    const char* Bb = (const char*)Wfb;

    for (int k0 = 0; k0 < 512; k0 += 32) {
        __syncthreads();
        #pragma unroll
        for (int q = 0; q < 2; ++q) {
            const int li = q * 4096 + wave * 1024 + lane * 16;
            const int rr = li >> 6, off = li & 63;
            gload_lds16(Ab + (size_t)(row0 + rr) * 1024 + k0 * 2 + off,
                        (char*)Als + (q * 4096 + wave * 1024));
            gload_lds16(Bb + (size_t)(c0 + rr) * 1024 + k0 * 2 + off,
                        (char*)Bls + (q * 4096 + wave * 1024));
        }
        __syncthreads();

        f16x8 af[4], bf[4];
        #pragma unroll
        for (int i = 0; i < 4; ++i)
            af[i] = *(const f16x8*)(&Als[(wm * 64 + i * 16 + r) * 32 + quad * 8]);
        #pragma unroll
        for (int j = 0; j < 4; ++j)
            bf[j] = *(const f16x8*)(&Bls[(wn * 64 + j * 16 + r) * 32 + quad * 8]);
        #pragma unroll
        for (int i = 0; i < 4; ++i)
            #pragma unroll
            for (int j = 0; j < 4; ++j)
                acc[i][j] = __builtin_amdgcn_mfma_f32_16x16x32_f16(af[i], bf[j], acc[i][j], 0, 0, 0);
    }

    const int tensor = c0 >> 9;   // block-uniform: 0=Q 1=K 2=V
    unsigned short* OutH = (tensor == 0) ? Qh : (tensor == 1) ? Kh : Vh;

    float mu[4][4], rs[4][4];
    if (tensor < 2) {
        #pragma unroll
        for (int i = 0; i < 4; ++i) {
            #pragma unroll
            for (int reg = 0; reg < 4; ++reg) {
                float sm = acc[i][0][reg] + acc[i][1][reg] + acc[i][2][reg] + acc[i][3][reg];
                sm += __shfl_xor(sm, 1); sm += __shfl_xor(sm, 2);
                sm += __shfl_xor(sm, 4); sm += __shfl_xor(sm, 8);
                const float muv = sm * (1.f / 64.f);
                float qv = 0.f;
                #pragma unroll
                for (int j = 0; j < 4; ++j) {
                    const float dv = acc[i][j][reg] - muv;
                    qv = fmaf(dv, dv, qv);
                }
                qv += __shfl_xor(qv, 1); qv += __shfl_xor(qv, 2);
                qv += __shfl_xor(qv, 4); qv += __shfl_xor(qv, 8);
                mu[i][reg] = muv;
                rs[i][reg] = rsqrtf(qv * (1.f / 64.f) + 1e-5f);
            }
        }
    }

    // C/D layout col=lane&15, row=quad*4+reg (verified m89).
    #pragma unroll
    for (int i = 0; i < 4; ++i) {
        #pragma unroll
        for (int j = 0; j < 4; ++j) {
            const int cc = (c0 & 511) + wn * 64 + j * 16 + r;
            const int h = cc >> 6, d = cc & 63;
            #pragma unroll
            for (int reg = 0; reg < 4; ++reg) {
                const int row = row0 + wm * 64 + i * 16 + quad * 4 + reg;
                const int b = row >> 13, n = row & 8191;
                float v = acc[i][j][reg];
                if (tensor < 2) v = (v - mu[i][reg]) * rs[i][reg];
                OutH[(((size_t)(b * HH + h) * NN + n) << 6) + d] = f2h(v);
            }
        }
    }
}

// ---------------- Kernel 2: gather-attention (f16 in, fp32 accum, f16 out) ----------------
// One wave per (b,h,n). Score: 64 lanes = 32 neighbors x 2 half-rows, fdot2.
// V phase split into (a) 32 independent prefetch loads into a register array
// (all in flight together, one vmcnt drain) then (b) the serial fdot2 chain.
// __launch_bounds__(256,2) lets the allocator keep ~100 VGPRs so the prefetch
// actually materializes (round-5 lesson: at 36 VGPR the compiler serializes).
// XCD swizzle: physical block p -> logical (p&7)*4096 + (p>>3).
__global__ __launch_bounds__(256, 2) void attn(
    const unsigned short* __restrict__ Qh, const unsigned short* __restrict__ Kh,
    const unsigned short* __restrict__ Vh,
    const int* __restrict__ idx, unsigned short* __restrict__ Ob)
{
    const int p = blockIdx.x;                       // 0..32767
    const int L = ((p & 7) << 12) | (p >> 3);       // XCD-contiguous logical id
    const int wid  = L * 4 + (threadIdx.x >> 6);    // 0..BHN-1
    const int lane = threadIdx.x & 63;
    const int bh = wid >> 13;
    const int n  = wid & 8191;
    const size_t base = (size_t)bh * NN * DK;

    const int k    = lane >> 1;
    const int half = lane & 1;
    const int g    = idx[n * KNB + k];              // pair-duplicated

    // half-row dot: 32 elements each, as 16 packed f16 pairs
    const uint4* q4 = (const uint4*)(Qh + base + ((size_t)n << 6) + half * 32);
    const uint4* k4 = (const uint4*)(Kh + base + ((size_t)g << 6) + half * 32);
    float acc = 0.f;
    #pragma unroll
    for (int c = 0; c < 4; ++c) {
        const uint4 qa = q4[c], ka = k4[c];
        acc = dot2h(qa.x, ka.x, acc);
        acc = dot2h(qa.y, ka.y, acc);
        acc = dot2h(qa.z, ka.z, acc);
        acc = dot2h(qa.w, ka.w, acc);
    }
    float s = (acc + __shfl_xor(acc, 1)) * 0.125f;  // 1/sqrt(64)

    // softmax over 32 distinct neighbors (values pair-duplicated):
    float m = s;
    #pragma unroll
    for (int off = 2; off <= 32; off <<= 1) m = fmaxf(m, __shfl_xor(m, off));
    const float e = __expf(s - m);
    float tot = e;
    #pragma unroll
    for (int off = 2; off <= 32; off <<= 1) tot += __shfl_xor(tot, off);
    const float pr = e / tot;

    // Pack neighbor-pair (p, g): lane 4j holds p_{2j}|p_{2j+1}<<16, g likewise.
    const unsigned prh = (unsigned)f2h(pr);
    const unsigned pp = prh | (((unsigned)__shfl_xor((int)prh, 2)) << 16);
    const unsigned gg = (unsigned)g | (((unsigned)__shfl_xor(g, 2)) << 16);

    // (a) prefetch: 32 independent 2B gather loads into registers
    unsigned v0[16], v1[16];
    #pragma unroll
    for (int j = 0; j < 16; ++j) {
        const unsigned gpair = (unsigned)__builtin_amdgcn_readlane((int)gg, j * 4);
        const int g0 = (int)(gpair & 0xffffu), g1 = (int)(gpair >> 16);
        v0[j] = Vh[base + ((size_t)g0 << 6) + lane];
        v1[j] = Vh[base + ((size_t)g1 << 6) + lane];
    }
    // (b) math: serial fdot2 chain over prefetched values
    float o = 0.f;
    #pragma unroll
    for (int j = 0; j < 16; ++j) {
        const unsigned ppair = (unsigned)__builtin_amdgcn_readlane((int)pp, j * 4);
        o = dot2h(v0[j] | (v1[j] << 16), ppair, o);
    }
    const int b = bh >> 3, h = bh & 7;
    Ob[((size_t)(b * NN + n)) * DD + h * DK + lane] = f2h(o);
}

// ---------------- Kernel 3: output projection, f16 MFMA ----------------
__global__ __launch_bounds__(256) void gemm_out(
    const unsigned short* __restrict__ Ob, const unsigned short* __restrict__ Wob,
    const float* __restrict__ bout, float* __restrict__ out)
{
    __shared__ unsigned short Als[128 * 32];
    __shared__ unsigned short Bls[128 * 32];
    const int tid  = threadIdx.x;
    const int wave = tid >> 6, lane = tid & 63;
    const int wm = wave >> 1, wn = wave & 1;
    const int quad = lane >> 4, r = lane & 15;
    const int row0 = blockIdx.x * 128;
    const int c0   = blockIdx.y * 128;

    f32x4 acc[4][4];
    #pragma unroll
    for (int i = 0; i < 4; ++i)
        #pragma unroll
        for (int j = 0; j < 4; ++j) acc[i][j] = (f32x4)0.f;

    const char* Ab = (const char*)Ob;
    const char* Bb = (const char*)Wob;

    for (int k0 = 0; k0 < 512; k0 += 32) {
        __syncthreads();
        #pragma unroll
        for (int q = 0; q < 2; ++q) {
            const int li = q * 4096 + wave * 1024 + lane * 16;
            const int rr = li >> 6, off = li & 63;
            gload_lds16(Ab + (size_t)(row0 + rr) * 1024 + k0 * 2 + off,
                        (char*)Als + (q * 4096 + wave * 1024));
            gload_lds16(Bb + (size_t)(c0 + rr) * 1024 + k0 * 2 + off,
                        (char*)Bls + (q * 4096 + wave * 1024));
        }
        __syncthreads();

        f16x8 af[4], bf[4];
        #pragma unroll
        for (int i = 0; i < 4; ++i)
            af[i] = *(const f16x8*)(&Als[(wm * 64 + i * 16 + r) * 32 + quad * 8]);
        #pragma unroll
        for (int j = 0; j < 4; ++j)
            bf[j] = *(const f16x8*)(&Bls[(wn * 64 + j * 16 + r) * 32 + quad * 8]);
        #pragma unroll
        for (int i = 0; i < 4; ++i)
            #pragma unroll
            for (int j = 0; j < 4; ++j)
                acc[i][j] = __builtin_amdgcn_mfma_f32_16x16x32_f16(af[i], bf[j], acc[i][j], 0, 0, 0);
    }

    #pragma unroll
    for (int i = 0; i < 4; ++i) {
        #pragma unroll
        for (int j = 0; j < 4; ++j) {
            const int colg = c0 + wn * 64 + j * 16 + r;
            const float bb = bout[colg];
            #pragma unroll
            for (int reg = 0; reg < 4; ++reg) {
                const int row = row0 + wm * 64 + i * 16 + quad * 4 + reg;
                out[((size_t)row << 9) + colg] = acc[i][j][reg] + bb;
            }
        }
    }
}

extern "C" void kernel_launch(void* const* d_in, const int* in_sizes, int n_in,
                              void* d_out, int out_size, void* d_ws, size_t ws_size,
                              hipStream_t stream)
{
    const float* x    = (const float*)d_in[0];
    const int*   idx  = (const int*)  d_in[1];
    const float* Wq   = (const float*)d_in[2];
    const float* Wk   = (const float*)d_in[3];
    const float* Wv   = (const float*)d_in[4];
    const float* Wout = (const float*)d_in[5];
    const float* bout = (const float*)d_in[6];

    char* ws = (char*)d_ws;
    unsigned short* Qh  = (unsigned short*)(ws);              // 16777216 B
    unsigned short* Kh  = (unsigned short*)(ws + 16777216);   // 16777216 B
    unsigned short* Vh  = (unsigned short*)(ws + 33554432);   // 16777216 B
    unsigned short* Xb  = (unsigned short*)(ws + 50331648);   // 16777216 B; aliased as Ob
    unsigned short* Ob  = Xb;
    unsigned short* Wfb = (unsigned short*)(ws + 67108864);   // 1572864 B (Wq|Wk|Wv rows)
    unsigned short* Wob = (unsigned short*)(ws + 68681728);   // 524288 B
    float* out = (float*)d_out;

    cvt_all<<<9216, 256, 0, stream>>>(x, Wq, Wk, Wv, Wout, Xb, Wfb, Wob);

    dim3 g1(BN / 128, 1536 / 128);
    gemm_qkv<<<g1, 256, 0, stream>>>(Xb, Wfb, Qh, Kh, Vh);

    attn<<<BHN / 4, 256, 0, stream>>>(Qh, Kh, Vh, idx, Ob);

    dim3 g2(BN / 128, 512 / 128);
    gemm_out<<<g2, 256, 0, stream>>>(Ob, Wob, bout, out);
}

// Round 7
// 228.669 us; speedup vs baseline: 1.0646x; 1.0019x over previous
//
#include <hip/hip_runtime.h>
#include <hip/hip_bf16.h>
#include <math.h>

#define BB 2
#define NN 8192
#define DD 512
#define HH 8
#define DK 64
#define KNB 32
#define BN (BB*NN)          // 16384 rows
#define BHN (BB*HH*NN)      // 131072 (b,h,n) tuples

typedef __attribute__((ext_vector_type(8))) _Float16 f16x8;   // 8 f16 in 4 VGPRs
typedef __attribute__((ext_vector_type(2))) _Float16 f16x2;
typedef __attribute__((ext_vector_type(4))) float f32x4;

#if __has_builtin(__builtin_amdgcn_fdot2)
#define HAS_FDOT2 1
#endif

__device__ __forceinline__ unsigned short f2h(float f) {
    return __builtin_bit_cast(unsigned short, (_Float16)f);
}
__device__ __forceinline__ f16x2 u2h2(unsigned u) {
    return __builtin_bit_cast(f16x2, u);
}
__device__ __forceinline__ float h2f_lo(unsigned u) {
    return (float)__builtin_bit_cast(_Float16, (unsigned short)(u & 0xffffu));
}
__device__ __forceinline__ float h2f_hi(unsigned u) {
    return (float)__builtin_bit_cast(_Float16, (unsigned short)(u >> 16));
}
// dot of packed f16 pairs with fp32 accumulate
__device__ __forceinline__ float dot2h(unsigned a, unsigned b, float c) {
#ifdef HAS_FDOT2
    return __builtin_amdgcn_fdot2(u2h2(a), u2h2(b), c, false);
#else
    c = fmaf(h2f_lo(a), h2f_lo(b), c);
    return fmaf(h2f_hi(a), h2f_hi(b), c);
#endif
}

// async global->LDS DMA. LDS dest is wave-uniform base; HW adds lane*width.
__device__ __forceinline__ void gload_lds16(const void* gptr, void* lptr) {
    __builtin_amdgcn_global_load_lds(
        (const __attribute__((address_space(1))) unsigned int*)gptr,
        (__attribute__((address_space(3))) unsigned int*)lptr,
        16, 0, 0);
}
__device__ __forceinline__ void gload_lds4(const void* gptr, void* lptr) {
    __builtin_amdgcn_global_load_lds(
        (const __attribute__((address_space(1))) unsigned int*)gptr,
        (__attribute__((address_space(3))) unsigned int*)lptr,
        4, 0, 0);
}

// ---------------- fp32 -> f16 converter (x + all weights, one launch) ----------------
__global__ __launch_bounds__(256) void cvt_all(
    const float* __restrict__ x,
    const float* __restrict__ Wq, const float* __restrict__ Wk,
    const float* __restrict__ Wv, const float* __restrict__ Wo,
    unsigned short* __restrict__ Xb, unsigned short* __restrict__ Wfb,
    unsigned short* __restrict__ Wob)
{
    const int blk = blockIdx.x;
    const float* src;
    unsigned short* dst;
    int off;
    if (blk < 8192) {
        off = (blk * 256 + threadIdx.x) * 4;
        src = x; dst = Xb;
    } else {
        const int e = ((blk - 8192) * 256 + threadIdx.x) * 4;   // over 4*262144
        const int t = e >> 18;
        off = e & 262143;
        src = (t == 0) ? Wq : (t == 1) ? Wk : (t == 2) ? Wv : Wo;
        dst = (t < 3) ? (Wfb + (size_t)t * 262144) : Wob;
    }
    const float4 v = *(const float4*)(src + off);
    ushort4 u;
    u.x = f2h(v.x); u.y = f2h(v.y); u.z = f2h(v.z); u.w = f2h(v.w);
    *(ushort4*)(dst + off) = u;
}

// ---------------- Kernel 1: fused QKV projection + LayerNorm, f16 MFMA ----------------
__global__ __launch_bounds__(256) void gemm_qkv(
    const unsigned short* __restrict__ Xb, const unsigned short* __restrict__ Wfb,
    unsigned short* __restrict__ Qh, unsigned short* __restrict__ Kh,
    unsigned short* __restrict__ Vh)
{
    __shared__ unsigned short Als[128 * 32];   // 8 KB
    __shared__ unsigned short Bls[128 * 32];   // 8 KB
    const int tid  = threadIdx.x;
    const int wave = tid >> 6, lane = tid & 63;
    const int wm = wave >> 1, wn = wave & 1;
    const int quad = lane >> 4, r = lane & 15;
    const int row0 = blockIdx.x * 128;
    const int c0   = blockIdx.y * 128;        // 128 | 512 so tile is within one tensor

    f32x4 acc[4][4];
    #pragma unroll
    for (int i = 0; i < 4; ++i)
        #pragma unroll
        for (int j = 0; j < 4; ++j) acc[i][j] = (f32x4)0.f;

    const char* Ab = (const char*)Xb;
    const char* Bb = (const char*)Wfb;

    for (int k0 = 0; k0 < 512; k0 += 32) {
        __syncthreads();
        #pragma unroll
        for (int q = 0; q < 2; ++q) {
            const int li = q * 4096 + wave * 1024 + lane * 16;
            const int rr = li >> 6, off = li & 63;
            gload_lds16(Ab + (size_t)(row0 + rr) * 1024 + k0 * 2 + off,
                        (char*)Als + (q * 4096 + wave * 1024));
            gload_lds16(Bb + (size_t)(c0 + rr) * 1024 + k0 * 2 + off,
                        (char*)Bls + (q * 4096 + wave * 1024));
        }
        __syncthreads();

        f16x8 af[4], bf[4];
        #pragma unroll
        for (int i = 0; i < 4; ++i)
            af[i] = *(const f16x8*)(&Als[(wm * 64 + i * 16 + r) * 32 + quad * 8]);
        #pragma unroll
        for (int j = 0; j < 4; ++j)
            bf[j] = *(const f16x8*)(&Bls[(wn * 64 + j * 16 + r) * 32 + quad * 8]);
        #pragma unroll
        for (int i = 0; i < 4; ++i)
            #pragma unroll
            for (int j = 0; j < 4; ++j)
                acc[i][j] = __builtin_amdgcn_mfma_f32_16x16x32_f16(af[i], bf[j], acc[i][j], 0, 0, 0);
    }

    const int tensor = c0 >> 9;   // block-uniform: 0=Q 1=K 2=V
    unsigned short* OutH = (tensor == 0) ? Qh : (tensor == 1) ? Kh : Vh;

    float mu[4][4], rs[4][4];
    if (tensor < 2) {
        #pragma unroll
        for (int i = 0; i < 4; ++i) {
            #pragma unroll
            for (int reg = 0; reg < 4; ++reg) {
                float sm = acc[i][0][reg] + acc[i][1][reg] + acc[i][2][reg] + acc[i][3][reg];
                sm += __shfl_xor(sm, 1); sm += __shfl_xor(sm, 2);
                sm += __shfl_xor(sm, 4); sm += __shfl_xor(sm, 8);
                const float muv = sm * (1.f / 64.f);
                float qv = 0.f;
                #pragma unroll
                for (int j = 0; j < 4; ++j) {
                    const float dv = acc[i][j][reg] - muv;
                    qv = fmaf(dv, dv, qv);
                }
                qv += __shfl_xor(qv, 1); qv += __shfl_xor(qv, 2);
                qv += __shfl_xor(qv, 4); qv += __shfl_xor(qv, 8);
                mu[i][reg] = muv;
                rs[i][reg] = rsqrtf(qv * (1.f / 64.f) + 1e-5f);
            }
        }
    }

    // C/D layout col=lane&15, row=quad*4+reg (verified m89).
    #pragma unroll
    for (int i = 0; i < 4; ++i) {
        #pragma unroll
        for (int j = 0; j < 4; ++j) {
            const int cc = (c0 & 511) + wn * 64 + j * 16 + r;
            const int h = cc >> 6, d = cc & 63;
            #pragma unroll
            for (int reg = 0; reg < 4; ++reg) {
                const int row = row0 + wm * 64 + i * 16 + quad * 4 + reg;
                const int b = row >> 13, n = row & 8191;
                float v = acc[i][j][reg];
                if (tensor < 2) v = (v - mu[i][reg]) * rs[i][reg];
                OutH[(((size_t)(b * HH + h) * NN + n) << 6) + d] = f2h(v);
            }
        }
    }
}

// ---------------- Kernel 2: gather-attention with async V staging ----------------
// One wave per (b,h,n). Phase order:
//   1. read idx, issue 16 width-4 global_load_lds DMAs staging all 32 V rows
//      into this wave's 4 KB LDS slab (async, vmcnt-tracked, no dest VGPRs --
//      the register allocator cannot serialize it; rounds 5/6 showed it
//      serializes any VGPR-destined prefetch at its preferred 36 VGPRs).
//   2. score phase (K gather + fdot2 + softmax) runs on top of the DMA.
//   3. __syncthreads() (drains vmcnt), then V accumulation reads LDS --
//      a chain the compiler pipelines with fine-grained lgkmcnt (m97 evidence).
// XCD swizzle: physical block p -> logical (p&7)*4096 + (p>>3).
__global__ __launch_bounds__(256, 2) void attn(
    const unsigned short* __restrict__ Qh, const unsigned short* __restrict__ Kh,
    const unsigned short* __restrict__ Vh,
    const int* __restrict__ idx, unsigned short* __restrict__ Ob)
{
    __shared__ unsigned short Vls[4][2048];         // per-wave 32 rows x 128 B
    const int p = blockIdx.x;                       // 0..32767
    const int L = ((p & 7) << 12) | (p >> 3);       // XCD-contiguous logical id
    const int wave = threadIdx.x >> 6;
    const int wid  = L * 4 + wave;                  // 0..BHN-1
    const int lane = threadIdx.x & 63;
    const int bh = wid >> 13;
    const int n  = wid & 8191;
    const size_t base = (size_t)bh * NN * DK;       // element offset of (b,h) slab

    const int k    = lane >> 1;
    const int half = lane & 1;
    const int g    = idx[n * KNB + k];              // pair-duplicated

    // Pack g pairs: lane 4j holds g_{2j} | g_{2j+1}<<16.
    const unsigned gg = (unsigned)g | (((unsigned)__shfl_xor(g, 2)) << 16);

    // Phase 1: stage all 32 V rows into LDS. Instr j: lanes 0..31 fetch row
    // g_{2j} (4 B each), lanes 32..63 fetch row g_{2j+1}; lands at lw + j*256.
    char* lw = (char*)Vls[wave];
    const char* Vbytes = (const char*)Vh + (base << 1);
    const int col4 = (lane & 31) * 4;
    const int sub  = lane >> 5;
    #pragma unroll
    for (int j = 0; j < 16; ++j) {
        const unsigned gpair = (unsigned)__builtin_amdgcn_readlane((int)gg, j * 4);
        const int grow = sub ? (int)(gpair >> 16) : (int)(gpair & 0xffffu);
        gload_lds4(Vbytes + grow * 128 + col4, lw + j * 256);
    }

    // Phase 2: score. Half-row dot: 32 elements each, as 16 packed f16 pairs.
    const uint4* q4 = (const uint4*)(Qh + base + ((size_t)n << 6) + half * 32);
    const uint4* k4 = (const uint4*)(Kh + base + ((size_t)g << 6) + half * 32);
    float acc = 0.f;
    #pragma unroll
    for (int c = 0; c < 4; ++c) {
        const uint4 qa = q4[c], ka = k4[c];
        acc = dot2h(qa.x, ka.x, acc);
        acc = dot2h(qa.y, ka.y, acc);
        acc = dot2h(qa.z, ka.z, acc);
        acc = dot2h(qa.w, ka.w, acc);
    }
    float s = (acc + __shfl_xor(acc, 1)) * 0.125f;  // 1/sqrt(64)

    // softmax over 32 distinct neighbors (values pair-duplicated):
    float m = s;
    #pragma unroll
    for (int off = 2; off <= 32; off <<= 1) m = fmaxf(m, __shfl_xor(m, off));
    const float e = __expf(s - m);
    float tot = e;
    #pragma unroll
    for (int off = 2; off <= 32; off <<= 1) tot += __shfl_xor(tot, off);
    const float pr = e / tot;

    // Pack p pairs (f16): lane 4j holds p_{2j} | p_{2j+1}<<16.
    const unsigned prh = (unsigned)f2h(pr);
    const unsigned pp = prh | (((unsigned)__shfl_xor((int)prh, 2)) << 16);

    // Phase 3: DMA visible after the barrier (vmcnt drained), then LDS chain.
    __syncthreads();
    const unsigned short* lv = (const unsigned short*)Vls[wave];
    float o = 0.f;
    #pragma unroll
    for (int j = 0; j < 16; ++j) {
        const unsigned ppair = (unsigned)__builtin_amdgcn_readlane((int)pp, j * 4);
        const unsigned v0 = lv[j * 128 + lane];         // row 2j,  dim=lane
        const unsigned v1 = lv[j * 128 + 64 + lane];    // row 2j+1, dim=lane
        o = dot2h(v0 | (v1 << 16), ppair, o);
    }
    const int b = bh >> 3, h = bh & 7;
    Ob[((size_t)(b * NN + n)) * DD + h * DK + lane] = f2h(o);
}

// ---------------- Kernel 3: output projection, f16 MFMA ----------------
__global__ __launch_bounds__(256) void gemm_out(
    const unsigned short* __restrict__ Ob, const unsigned short* __restrict__ Wob,
    const float* __restrict__ bout, float* __restrict__ out)
{
    __shared__ unsigned short Als[128 * 32];
    __shared__ unsigned short Bls[128 * 32];
    const int tid  = threadIdx.x;
    const int wave = tid >> 6, lane = tid & 63;
    const int wm = wave >> 1, wn = wave & 1;
    const int quad = lane >> 4, r = lane & 15;
    const int row0 = blockIdx.x * 128;
    const int c0   = blockIdx.y * 128;

    f32x4 acc[4][4];
    #pragma unroll
    for (int i = 0; i < 4; ++i)
        #pragma unroll
        for (int j = 0; j < 4; ++j) acc[i][j] = (f32x4)0.f;

    const char* Ab = (const char*)Ob;
    const char* Bb = (const char*)Wob;

    for (int k0 = 0; k0 < 512; k0 += 32) {
        __syncthreads();
        #pragma unroll
        for (int q = 0; q < 2; ++q) {
            const int li = q * 4096 + wave * 1024 + lane * 16;
            const int rr = li >> 6, off = li & 63;
            gload_lds16(Ab + (size_t)(row0 + rr) * 1024 + k0 * 2 + off,
                        (char*)Als + (q * 4096 + wave * 1024));
            gload_lds16(Bb + (size_t)(c0 + rr) * 1024 + k0 * 2 + off,
                        (char*)Bls + (q * 4096 + wave * 1024));
        }
        __syncthreads();

        f16x8 af[4], bf[4];
        #pragma unroll
        for (int i = 0; i < 4; ++i)
            af[i] = *(const f16x8*)(&Als[(wm * 64 + i * 16 + r) * 32 + quad * 8]);
        #pragma unroll
        for (int j = 0; j < 4; ++j)
            bf[j] = *(const f16x8*)(&Bls[(wn * 64 + j * 16 + r) * 32 + quad * 8]);
        #pragma unroll
        for (int i = 0; i < 4; ++i)
            #pragma unroll
            for (int j = 0; j < 4; ++j)
                acc[i][j] = __builtin_amdgcn_mfma_f32_16x16x32_f16(af[i], bf[j], acc[i][j], 0, 0, 0);
    }

    #pragma unroll
    for (int i = 0; i < 4; ++i) {
        #pragma unroll
        for (int j = 0; j < 4; ++j) {
            const int colg = c0 + wn * 64 + j * 16 + r;
            const float bb = bout[colg];
            #pragma unroll
            for (int reg = 0; reg < 4; ++reg) {
                const int row = row0 + wm * 64 + i * 16 + quad * 4 + reg;
                out[((size_t)row << 9) + colg] = acc[i][j][reg] + bb;
            }
        }
    }
}

extern "C" void kernel_launch(void* const* d_in, const int* in_sizes, int n_in,
                              void* d_out, int out_size, void* d_ws, size_t ws_size,
                              hipStream_t stream)
{
    const float* x    = (const float*)d_in[0];
    const int*   idx  = (const int*)  d_in[1];
    const float* Wq   = (const float*)d_in[2];
    const float* Wk   = (const float*)d_in[3];
    const float* Wv   = (const float*)d_in[4];
    const float* Wout = (const float*)d_in[5];
    const float* bout = (const float*)d_in[6];

    char* ws = (char*)d_ws;
    unsigned short* Qh  = (unsigned short*)(ws);              // 16777216 B
    unsigned short* Kh  = (unsigned short*)(ws + 16777216);   // 16777216 B
    unsigned short* Vh  = (unsigned short*)(ws + 33554432);   // 16777216 B
    unsigned short* Xb  = (unsigned short*)(ws + 50331648);   // 16777216 B; aliased as Ob
    unsigned short* Ob  = Xb;
    unsigned short* Wfb = (unsigned short*)(ws + 67108864);   // 1572864 B (Wq|Wk|Wv rows)
    unsigned short* Wob = (unsigned short*)(ws + 68681728);   // 524288 B
    float* out = (float*)d_out;

    cvt_all<<<9216, 256, 0, stream>>>(x, Wq, Wk, Wv, Wout, Xb, Wfb, Wob);

    dim3 g1(BN / 128, 1536 / 128);
    gemm_qkv<<<g1, 256, 0, stream>>>(Xb, Wfb, Qh, Kh, Vh);

    attn<<<BHN / 4, 256, 0, stream>>>(Qh, Kh, Vh, idx, Ob);

    dim3 g2(BN / 128, 512 / 128);
    gemm_out<<<g2, 256, 0, stream>>>(Ob, Wob, bout, out);
}